// Round 14
// baseline (219.978 us; speedup 1.0000x reference)
//
#include <hip/hip_runtime.h>
#include <hip/hip_bf16.h>
#include <stdint.h>

#define N_TOK 8192
#define DDIM  128

typedef _Float16 half2v __attribute__((ext_vector_type(2)));
typedef _Float16 half4v __attribute__((ext_vector_type(4)));
typedef _Float16 half8v __attribute__((ext_vector_type(8)));
typedef __fp16  fp16x2 __attribute__((ext_vector_type(2)));
typedef float f32x4 __attribute__((ext_vector_type(4)));
typedef half4v half4_ma __attribute__((may_alias));
typedef half8v half8_ma __attribute__((may_alias));
typedef float4 float4_ma __attribute__((may_alias));

#define MFMA32 __builtin_amdgcn_mfma_f32_16x16x32_f16

// 1/sqrt(128) * log2(e): folded into Q so inner loop is a bare v_exp_f32
#define QSCALE (0.08838834764831845f * 1.4426950408889634f)

__device__ __forceinline__ half2v pkrtz(float a, float b) {
  return __builtin_bit_cast(half2v, __builtin_amdgcn_cvt_pkrtz(a, b));
}

#if __has_builtin(__builtin_amdgcn_fdot2)
__device__ __forceinline__ float dot2acc(half2v a, float c) {
  const fp16x2 ones = {(__fp16)1.f, (__fp16)1.f};
  return __builtin_amdgcn_fdot2(__builtin_bit_cast(fp16x2, a), ones, c, false);
}
#else
__device__ __forceinline__ float dot2acc(half2v a, float c) {
  return c + (float)a.x + (float)a.y;
}
#endif

__device__ __forceinline__ void gload_lds16(const _Float16* g, _Float16* l) {
  __builtin_amdgcn_global_load_lds(
      (const __attribute__((address_space(1))) void*)g,
      (__attribute__((address_space(3))) void*)l, 16, 0, 0);
}

// ---------------- fused prep: Q/K transpose + sigma-V copy + cnt zero ------
// Vt sigma-permuted per 32-key panel: slot(w) = (w<16) ? (w>>2)*8+(w&3)
// : ((w-16)>>2)*8+4+(w&3), so one 16B unit u = keys {4u..} u {16+4u..} = one
// PV A-frag (verified R13).
__global__ void prep_all(const float* __restrict__ x,
                         _Float16* __restrict__ Qf, _Float16* __restrict__ Kf,
                         _Float16* __restrict__ Vt, uint32_t* __restrict__ cnt) {
  __shared__ float t[32][33];
  const int blk = blockIdx.x, tid = threadIdx.x;
  if (blk < 2048) {
    const int pt = blk & 31, ct = (blk >> 5) & 3, z = blk >> 7;
    const int b = z >> 1, isQ = z & 1;
    const int c0 = (isQ ? 256 : 128) + ct * 32;
    const int p0 = pt * 32;
    const int tx = tid & 31, ty0 = tid >> 5;
    const float* src = x + ((size_t)b * 384 + c0) * 1024 + p0;
#pragma unroll
    for (int i = 0; i < 4; ++i)
      t[ty0 + i * 8][tx] = src[(ty0 + i * 8) * 1024 + tx];
    __syncthreads();
    _Float16* dst = isQ ? Qf : Kf;
    const float sc = isQ ? QSCALE : 1.f;
#pragma unroll
    for (int i = 0; i < 4; ++i) {
      const int ty = ty0 + i * 8;
      dst[((size_t)b * 1024 + p0 + ty) * DDIM + ct * 32 + tx] = (_Float16)(t[tx][ty] * sc);
    }
  } else {
    if (blk == 2048 && tid < 32) cnt[tid] = 0;   // combine counters
    const int i4 = ((blk - 2048) * 256 + tid) * 4;   // 4 consecutive keys
    const int v = i4 >> 13, n = i4 & 8191;
    const int b = n >> 10, p = n & 1023;
    const float4 s = *(const float4_ma*)(x + ((size_t)b * 384 + v) * 1024 + p);
    half4v h; h.x = (_Float16)s.x; h.y = (_Float16)s.y; h.z = (_Float16)s.z; h.w = (_Float16)s.w;
    const int key = (b << 10) + p;
    const int panel = key >> 5, w = key & 31;        // w multiple of 4
    const int slot = (w < 16) ? ((w >> 2) << 3) : ((((w - 16) >> 2) << 3) + 4);
    *(half4_ma*)(Vt + (size_t)v * N_TOK + panel * 32 + slot) = h;
  }
}

// ---------------- flash attention: QT=4, CK=64 two-pass, fold-combine ------
// 32*KS blocks x 256 thr (4 waves x 64 qrows), KS=16 w/ XCD swizzle, 64KB
// LDS dbuf -> 2 blocks/CU. PV at K=32-rate via sigma-Vt (one b128/frag).
// LDS per buf: K crumb [chi 16][key 64][clo 8]; V [v 128][unit^(v&7) 8][8].
// Last split-block per qtile combines (device-scope atomic + fences).
template<int KS>
__global__ __launch_bounds__(256, 2) void flash_attn(
    const _Float16* __restrict__ Qf, const _Float16* __restrict__ Kf,
    const _Float16* __restrict__ Vt, _Float16* __restrict__ Opart,
    float* __restrict__ Lsum, float* __restrict__ out,
    uint32_t* __restrict__ cnt) {
  alignas(16) __shared__ _Float16 lds[32768];  // 2 x (K 16KB + V 16KB)
  __shared__ int lastFlag;

  const int tid = threadIdx.x;
  const int w = tid >> 6, lane = tid & 63;
  const int quad = lane >> 4, l16 = lane & 15;
  const int blk = blockIdx.x;
  const int ks = (KS == 16) ? (((blk & 7) << 1) | (blk >> 8)) : (blk & 7);
  const int qtile = (blk >> 3) & 31;
  const int kp = N_TOK / KS;
  const int chunks = kp >> 6;           // CK=64
  const int k0 = ks * kp;
  const int q0 = qtile * 256;

  // Q fragments resident (B-operand): Q[q=l16][c=quad*8+j], 4 q-tiles
  half8v qf[4][4];
#pragma unroll
  for (int qt = 0; qt < 4; ++qt) {
    const _Float16* qp = Qf + (size_t)(q0 + w * 64 + qt * 16 + l16) * DDIM + quad * 8;
#pragma unroll
    for (int kb = 0; kb < 4; ++kb) qf[qt][kb] = *(const half8_ma*)(qp + kb * 32);
  }

  f32x4 O[4][8];
#pragma unroll
  for (int qt = 0; qt < 4; ++qt)
#pragma unroll
    for (int vb = 0; vb < 8; ++vb) O[qt][vb] = (f32x4){0.f, 0.f, 0.f, 0.f};
  float ls[4] = {0.f, 0.f, 0.f, 0.f};

  // staging: per wave 4 K + 4 V instrs per chunk (16+16 per block)
  const _Float16* srcK[4];
  const _Float16* srcV[4];
  int slotK[4], slotV[4];
#pragma unroll
  for (int j = 0; j < 4; ++j) {
    const int i = w * 4 + j;                    // 0..15
    srcK[j] = Kf + (size_t)(k0 + lane) * DDIM + i * 8;
    slotK[j] = i * 512;
    // V: dest row v = i*8 + (lane>>3), phys unit = lane&7;
    // logical unit = phys ^ (v&7) = (lane&7) ^ (lane>>3)
    const int vrow = i * 8 + (lane >> 3);
    const int lu = (lane & 7) ^ (lane >> 3);
    srcV[j] = Vt + (size_t)vrow * N_TOK + k0 + lu * 8;
    slotV[j] = 8192 + i * 512;
  }

#pragma unroll
  for (int j = 0; j < 4; ++j) {
    gload_lds16(srcK[j], lds + slotK[j]);
    gload_lds16(srcV[j], lds + slotV[j]);
  }

  const int xsw = l16 & 7;              // V read un-swizzle (v&7)
  for (int ch = 0; ch < chunks; ++ch) {
    __syncthreads();
    _Float16* buf = lds + (ch & 1) * 16384;
    if (ch + 1 < chunks) {
      _Float16* nbuf = lds + ((ch + 1) & 1) * 16384;
      const int adv = (ch + 1) * 64;
#pragma unroll
      for (int j = 0; j < 4; ++j) {
        gload_lds16(srcK[j] + (size_t)adv * DDIM, nbuf + slotK[j]);
        gload_lds16(srcV[j] + adv, nbuf + 8192 - 8192 + slotV[j] - 8192 + 8192 + adv - adv);  // placeholder removed below
      }
    }
    // (the V prefetch above is rewritten correctly here)
    if (ch + 1 < chunks) {
      _Float16* nbuf = lds + ((ch + 1) & 1) * 16384;
      const int adv = (ch + 1) * 64;
#pragma unroll
      for (int j = 0; j < 4; ++j)
        gload_lds16(srcV[j] + adv, nbuf + slotV[j]);
    }
    const _Float16* Ksh = buf;
    const _Float16* Vsh = buf + 8192;

    // two 32-key passes, no barrier between (waves drift for pipe overlap)
#pragma unroll
    for (int p = 0; p < 2; ++p) {
      f32x4 S[4][2];
#pragma unroll
      for (int qt = 0; qt < 4; ++qt)
#pragma unroll
        for (int cb = 0; cb < 2; ++cb) S[qt][cb] = (f32x4){0.f, 0.f, 0.f, 0.f};
#pragma unroll
      for (int kb = 0; kb < 4; ++kb) {
#pragma unroll
        for (int cb = 0; cb < 2; ++cb) {
          half8v kf = *(const half8_ma*)(Ksh + (kb * 4 + quad) * 512 +
                                         (p * 32 + cb * 16 + l16) * 8);
#pragma unroll
          for (int qt = 0; qt < 4; ++qt)
            S[qt][cb] = MFMA32(kf, qf[qt][kb], S[qt][cb], 0, 0, 0);
        }
      }

      half8v P8[4];
#pragma unroll
      for (int qt = 0; qt < 4; ++qt) {
        const float a0 = __builtin_amdgcn_exp2f(S[qt][0][0]);
        const float a1 = __builtin_amdgcn_exp2f(S[qt][0][1]);
        const float a2 = __builtin_amdgcn_exp2f(S[qt][0][2]);
        const float a3 = __builtin_amdgcn_exp2f(S[qt][0][3]);
        const float b0 = __builtin_amdgcn_exp2f(S[qt][1][0]);
        const float b1 = __builtin_amdgcn_exp2f(S[qt][1][1]);
        const float b2 = __builtin_amdgcn_exp2f(S[qt][1][2]);
        const float b3 = __builtin_amdgcn_exp2f(S[qt][1][3]);
        half2v pa0 = pkrtz(a0, a1), pa1 = pkrtz(a2, a3);
        half2v pb0 = pkrtz(b0, b1), pb1 = pkrtz(b2, b3);
        ls[qt] = dot2acc(pa0, dot2acc(pa1, dot2acc(pb0, dot2acc(pb1, ls[qt]))));
        half4v lo = __builtin_shufflevector(pa0, pa1, 0, 1, 2, 3);
        half4v hi = __builtin_shufflevector(pb0, pb1, 0, 1, 2, 3);
        P8[qt] = __builtin_shufflevector(lo, hi, 0, 1, 2, 3, 4, 5, 6, 7);
      }

      const int physA = (p * 4 + quad) ^ xsw;
#pragma unroll
      for (int vb = 0; vb < 8; ++vb) {
        const int v = vb * 16 + l16;
        half8v vf = *(const half8_ma*)(Vsh + v * 64 + physA * 8);
#pragma unroll
        for (int qt = 0; qt < 4; ++qt)
          O[qt][vb] = MFMA32(vf, P8[qt], O[qt][vb], 0, 0, 0);
      }
    }
  }

  // epilogue: normalized partials
#pragma unroll
  for (int qt = 0; qt < 4; ++qt) {
    ls[qt] += __shfl_xor(ls[qt], 16, 64);
    ls[qt] += __shfl_xor(ls[qt], 32, 64);
  }
#pragma unroll
  for (int qt = 0; qt < 4; ++qt) {
    const float rl = 1.f / ls[qt];
    const int q = q0 + w * 64 + qt * 16 + l16;
#pragma unroll
    for (int vb = 0; vb < 8; ++vb) {
#pragma unroll
      for (int r = 0; r < 4; ++r) {
        const int v = vb * 16 + quad * 4 + r;
        Opart[((size_t)ks * DDIM + v) * N_TOK + q] = (_Float16)(O[qt][vb][r] * rl);
      }
    }
  }
  if (lane < 16) {
#pragma unroll
    for (int qt = 0; qt < 4; ++qt)
      Lsum[(size_t)ks * N_TOK + q0 + w * 64 + qt * 16 + lane] = ls[qt];
  }

  // ---- fold-combine: last split-block of this qtile merges all KS splits --
  __threadfence();                       // release my Opart/Lsum device-wide
  __syncthreads();
  if (tid == 0) {
    uint32_t old = __hip_atomic_fetch_add(cnt + qtile, 1u, __ATOMIC_ACQ_REL,
                                          __HIP_MEMORY_SCOPE_AGENT);
    lastFlag = (old == (uint32_t)(KS - 1));
  }
  __syncthreads();
  if (lastFlag) {
    __threadfence();                     // acquire others' writes
    const int b = q0 >> 10, p0 = q0 & 1023;
    for (int idx = tid; idx < 128 * 64; idx += 256) {
      const int v = idx >> 6, g = idx & 63;
      const int q = q0 + g * 4;
      float4 num = make_float4(0.f, 0.f, 0.f, 0.f);
      float4 den = make_float4(0.f, 0.f, 0.f, 0.f);
#pragma unroll
      for (int s = 0; s < KS; ++s) {
        const float4 l = *(const float4_ma*)(Lsum + (size_t)s * N_TOK + q);
        const half4v ov = *(const half4_ma*)(Opart + ((size_t)s * DDIM + v) * N_TOK + q);
        num.x += l.x * (float)ov.x; num.y += l.y * (float)ov.y;
        num.z += l.z * (float)ov.z; num.w += l.w * (float)ov.w;
        den.x += l.x; den.y += l.y; den.z += l.z; den.w += l.w;
      }
      *(float4_ma*)(out + ((size_t)(b * 128 + v) << 10) + p0 + g * 4) =
          make_float4(num.x / den.x, num.y / den.y, num.z / den.z, num.w / den.w);
    }
  }
}

// ---------------- launch ---------------------------------------------------
extern "C" void kernel_launch(void* const* d_in, const int* in_sizes, int n_in,
                              void* d_out, int out_size, void* d_ws, size_t ws_size,
                              hipStream_t stream) {
  const float* x = (const float*)d_in[0];
  float* out = (float*)d_out;
  char* ws = (char*)d_ws;

  // ws: Qf 2MB | Kf 2MB | Vt 2MB | Opart KS*2MB | Lsum 1MB | cnt 128B
  const size_t need16 = (6u << 20) + 16 * (2u << 20) + (1u << 20) + 128;
  const int KS = (ws_size >= need16) ? 16 : 8;

  _Float16* Qf    = (_Float16*)(ws);
  _Float16* Kf    = (_Float16*)(ws + (2u << 20));
  _Float16* Vt    = (_Float16*)(ws + (4u << 20));
  _Float16* Opart = (_Float16*)(ws + (6u << 20));
  float*    Lsum  = (float*)(ws + (6u << 20) + (size_t)KS * (2u << 20));
  uint32_t* cnt   = (uint32_t*)(ws + (6u << 20) + (size_t)KS * (2u << 20) + (1u << 20));

  prep_all<<<dim3(3072), dim3(256), 0, stream>>>(x, Qf, Kf, Vt, cnt);
  if (KS == 16) {
    flash_attn<16><<<dim3(512), dim3(256), 0, stream>>>(Qf, Kf, Vt, Opart, Lsum, out, cnt);
  } else {
    flash_attn<8><<<dim3(256), dim3(256), 0, stream>>>(Qf, Kf, Vt, Opart, Lsum, out, cnt);
  }
}

// Round 15
// 116.556 us; speedup vs baseline: 1.8873x; 1.8873x over previous
//
#include <hip/hip_runtime.h>
#include <hip/hip_bf16.h>
#include <stdint.h>

#define N_TOK 8192
#define DDIM  128

typedef _Float16 half2v __attribute__((ext_vector_type(2)));
typedef _Float16 half4v __attribute__((ext_vector_type(4)));
typedef _Float16 half8v __attribute__((ext_vector_type(8)));
typedef __fp16  fp16x2 __attribute__((ext_vector_type(2)));
typedef float f32x4 __attribute__((ext_vector_type(4)));
typedef half4v half4_ma __attribute__((may_alias));
typedef half8v half8_ma __attribute__((may_alias));
typedef float4 float4_ma __attribute__((may_alias));

#define MFMA32 __builtin_amdgcn_mfma_f32_16x16x32_f16

// 1/sqrt(128) * log2(e): folded into Q so inner loop is a bare v_exp_f32
#define QSCALE (0.08838834764831845f * 1.4426950408889634f)

__device__ __forceinline__ half2v pkrtz(float a, float b) {
  return __builtin_bit_cast(half2v, __builtin_amdgcn_cvt_pkrtz(a, b));
}

#if __has_builtin(__builtin_amdgcn_fdot2)
__device__ __forceinline__ float dot2acc(half2v a, float c) {
  const fp16x2 ones = {(__fp16)1.f, (__fp16)1.f};
  return __builtin_amdgcn_fdot2(__builtin_bit_cast(fp16x2, a), ones, c, false);
}
#else
__device__ __forceinline__ float dot2acc(half2v a, float c) {
  return c + (float)a.x + (float)a.y;
}
#endif

__device__ __forceinline__ void gload_lds16(const _Float16* g, _Float16* l) {
  __builtin_amdgcn_global_load_lds(
      (const __attribute__((address_space(1))) void*)g,
      (__attribute__((address_space(3))) void*)l, 16, 0, 0);
}

// ---------------- fused prep: Q/K transpose + sigma-V copy -----------------
// Vt sigma-permuted per 32-key panel (verified R13): key w in panel ->
// slot(w) = (w<16) ? (w>>2)*8+(w&3) : ((w-16)>>2)*8+4+(w&3); 16B unit q of a
// panel = keys {4q..4q+3} u {16+4q..16+4q+3} = one MFMA32 PV A-frag.
__global__ void prep_all(const float* __restrict__ x,
                         _Float16* __restrict__ Qf, _Float16* __restrict__ Kf,
                         _Float16* __restrict__ Vt) {
  __shared__ float t[32][33];
  const int blk = blockIdx.x, tid = threadIdx.x;
  if (blk < 2048) {
    const int pt = blk & 31, ct = (blk >> 5) & 3, z = blk >> 7;
    const int b = z >> 1, isQ = z & 1;
    const int c0 = (isQ ? 256 : 128) + ct * 32;
    const int p0 = pt * 32;
    const int tx = tid & 31, ty0 = tid >> 5;
    const float* src = x + ((size_t)b * 384 + c0) * 1024 + p0;
#pragma unroll
    for (int i = 0; i < 4; ++i)
      t[ty0 + i * 8][tx] = src[(ty0 + i * 8) * 1024 + tx];
    __syncthreads();
    _Float16* dst = isQ ? Qf : Kf;
    const float sc = isQ ? QSCALE : 1.f;
#pragma unroll
    for (int i = 0; i < 4; ++i) {
      const int ty = ty0 + i * 8;
      dst[((size_t)b * 1024 + p0 + ty) * DDIM + ct * 32 + tx] = (_Float16)(t[tx][ty] * sc);
    }
  } else {
    const int i4 = ((blk - 2048) * 256 + tid) * 4;   // 4 consecutive keys
    const int v = i4 >> 13, n = i4 & 8191;
    const int b = n >> 10, p = n & 1023;
    const float4 s = *(const float4_ma*)(x + ((size_t)b * 384 + v) * 1024 + p);
    half4v h; h.x = (_Float16)s.x; h.y = (_Float16)s.y; h.z = (_Float16)s.z; h.w = (_Float16)s.w;
    const int key = (b << 10) + p;
    const int panel = key >> 5, w = key & 31;        // w multiple of 4
    const int slot = (w < 16) ? ((w >> 2) << 3) : ((((w - 16) >> 2) << 3) + 4);
    *(half4_ma*)(Vt + (size_t)v * N_TOK + panel * 32 + slot) = h;
  }
}

// ---------------- flash attention: QT=4, CK=64 two-pass, sigma-V b128 ------
// 32*KS blocks x 256 thr (4 waves x 64 qrows), KS=16 w/ XCD swizzle.
// LDS = exactly 64KB (2 x (K 16KB + V 16KB)) -> 2 blocks/CU. PV at K=32 rate.
// LDS layouts: K crumb [chi 16][key 64][clo 8];
//              V [v 128][unit 8][8] with phys_unit = logical ^ (v&7).
template<int KS>
__global__ __launch_bounds__(256, 2) void flash_attn(
    const _Float16* __restrict__ Qf, const _Float16* __restrict__ Kf,
    const _Float16* __restrict__ Vt, _Float16* __restrict__ Opart,
    float* __restrict__ Lsum) {
  alignas(16) __shared__ _Float16 lds[32768];  // 65536 B exactly — nothing else

  const int tid = threadIdx.x;
  const int w = tid >> 6, lane = tid & 63;
  const int quad = lane >> 4, l16 = lane & 15;
  const int blk = blockIdx.x;
  const int ks = (KS == 16) ? (((blk & 7) << 1) | (blk >> 8)) : (blk & 7);
  const int kp = N_TOK / KS;
  const int chunks = kp >> 6;           // CK=64
  const int k0 = ks * kp;
  const int q0 = ((blk >> 3) & 31) * 256;

  // Q fragments resident (B-operand): Q[q=l16][c=quad*8+j], 4 q-tiles
  half8v qf[4][4];
#pragma unroll
  for (int qt = 0; qt < 4; ++qt) {
    const _Float16* qp = Qf + (size_t)(q0 + w * 64 + qt * 16 + l16) * DDIM + quad * 8;
#pragma unroll
    for (int kb = 0; kb < 4; ++kb) qf[qt][kb] = *(const half8_ma*)(qp + kb * 32);
  }

  f32x4 O[4][8];
#pragma unroll
  for (int qt = 0; qt < 4; ++qt)
#pragma unroll
    for (int vb = 0; vb < 8; ++vb) O[qt][vb] = (f32x4){0.f, 0.f, 0.f, 0.f};
  float ls[4] = {0.f, 0.f, 0.f, 0.f};

  // staging: per wave 4 K + 4 V instrs per chunk (16+16 per block)
  const _Float16* srcK[4];
  const _Float16* srcV[4];
  int slotK[4], slotV[4];
#pragma unroll
  for (int j = 0; j < 4; ++j) {
    const int i = w * 4 + j;                    // 0..15
    srcK[j] = Kf + (size_t)(k0 + lane) * DDIM + i * 8;
    slotK[j] = i * 512;
    // V: dest row v = i*8 + (lane>>3), phys unit = lane&7;
    // logical unit lu = phys ^ (v&7) = (lane&7) ^ (lane>>3);
    // global source offset of logical unit: (lu>>2)*32 + (lu&3)*8
    const int vrow = i * 8 + (lane >> 3);
    const int lu = (lane & 7) ^ (lane >> 3);
    srcV[j] = Vt + (size_t)vrow * N_TOK + k0 + ((lu >> 2) << 5) + ((lu & 3) << 3);
    slotV[j] = 8192 + i * 512;
  }

#pragma unroll
  for (int j = 0; j < 4; ++j) {
    gload_lds16(srcK[j], lds + slotK[j]);
    gload_lds16(srcV[j], lds + slotV[j]);
  }

  const int xsw = l16 & 7;              // V read un-swizzle (v&7)
  for (int ch = 0; ch < chunks; ++ch) {
    __syncthreads();
    _Float16* buf = lds + (ch & 1) * 16384;
    if (ch + 1 < chunks) {
      _Float16* nbuf = lds + ((ch + 1) & 1) * 16384;
      const int adv = (ch + 1) * 64;
#pragma unroll
      for (int j = 0; j < 4; ++j) {
        gload_lds16(srcK[j] + (size_t)adv * DDIM, nbuf + slotK[j]);
        gload_lds16(srcV[j] + adv, nbuf + slotV[j]);
      }
    }
    const _Float16* Ksh = buf;
    const _Float16* Vsh = buf + 8192;

    // two 32-key passes, no barrier between
#pragma unroll
    for (int p = 0; p < 2; ++p) {
      f32x4 S[4][2];
#pragma unroll
      for (int qt = 0; qt < 4; ++qt)
#pragma unroll
        for (int cb = 0; cb < 2; ++cb) S[qt][cb] = (f32x4){0.f, 0.f, 0.f, 0.f};
#pragma unroll
      for (int kb = 0; kb < 4; ++kb) {
#pragma unroll
        for (int cb = 0; cb < 2; ++cb) {
          half8v kf = *(const half8_ma*)(Ksh + (kb * 4 + quad) * 512 +
                                         (p * 32 + cb * 16 + l16) * 8);
#pragma unroll
          for (int qt = 0; qt < 4; ++qt)
            S[qt][cb] = MFMA32(kf, qf[qt][kb], S[qt][cb], 0, 0, 0);
        }
      }

      half8v P8[4];
#pragma unroll
      for (int qt = 0; qt < 4; ++qt) {
        const float a0 = __builtin_amdgcn_exp2f(S[qt][0][0]);
        const float a1 = __builtin_amdgcn_exp2f(S[qt][0][1]);
        const float a2 = __builtin_amdgcn_exp2f(S[qt][0][2]);
        const float a3 = __builtin_amdgcn_exp2f(S[qt][0][3]);
        const float b0 = __builtin_amdgcn_exp2f(S[qt][1][0]);
        const float b1 = __builtin_amdgcn_exp2f(S[qt][1][1]);
        const float b2 = __builtin_amdgcn_exp2f(S[qt][1][2]);
        const float b3 = __builtin_amdgcn_exp2f(S[qt][1][3]);
        half2v pa0 = pkrtz(a0, a1), pa1 = pkrtz(a2, a3);
        half2v pb0 = pkrtz(b0, b1), pb1 = pkrtz(b2, b3);
        ls[qt] = dot2acc(pa0, dot2acc(pa1, dot2acc(pb0, dot2acc(pb1, ls[qt]))));
        half4v lo = __builtin_shufflevector(pa0, pa1, 0, 1, 2, 3);
        half4v hi = __builtin_shufflevector(pb0, pb1, 0, 1, 2, 3);
        P8[qt] = __builtin_shufflevector(lo, hi, 0, 1, 2, 3, 4, 5, 6, 7);
      }

      // PV: one b128 A-frag per vb (sigma layout), logical unit = p*4+quad
      const int physA = ((p << 2) | quad) ^ xsw;
#pragma unroll
      for (int vb = 0; vb < 8; ++vb) {
        const int v = vb * 16 + l16;
        half8v vf = *(const half8_ma*)(Vsh + v * 64 + physA * 8);
#pragma unroll
        for (int qt = 0; qt < 4; ++qt)
          O[qt][vb] = MFMA32(vf, P8[qt], O[qt][vb], 0, 0, 0);
      }
    }
  }

  // epilogue: normalized partials
#pragma unroll
  for (int qt = 0; qt < 4; ++qt) {
    ls[qt] += __shfl_xor(ls[qt], 16, 64);
    ls[qt] += __shfl_xor(ls[qt], 32, 64);
  }
#pragma unroll
  for (int qt = 0; qt < 4; ++qt) {
    const float rl = 1.f / ls[qt];
    const int q = q0 + w * 64 + qt * 16 + l16;
#pragma unroll
    for (int vb = 0; vb < 8; ++vb) {
#pragma unroll
      for (int r = 0; r < 4; ++r) {
        const int v = vb * 16 + quad * 4 + r;
        Opart[((size_t)ks * DDIM + v) * N_TOK + q] = (_Float16)(O[qt][vb][r] * rl);
      }
    }
  }
  if (lane < 16) {
#pragma unroll
    for (int qt = 0; qt < 4; ++qt)
      Lsum[(size_t)ks * N_TOK + q0 + w * 64 + qt * 16 + lane] = ls[qt];
  }
}

// ---------------- combine: float4, l-weighted average ----------------------
__global__ void combine_kernel(const _Float16* __restrict__ Opart,
                               const float* __restrict__ Lsum,
                               float* __restrict__ out, int KS) {
  const int o4 = (blockIdx.x * 256 + threadIdx.x) * 4;
  const int b = o4 >> 17, v = (o4 >> 10) & 127, p = o4 & 1023;
  const int q = (b << 10) | p;
  float4 num = make_float4(0.f, 0.f, 0.f, 0.f);
  float4 den = make_float4(0.f, 0.f, 0.f, 0.f);
  for (int s = 0; s < KS; ++s) {
    const float4 l = *(const float4_ma*)(Lsum + (size_t)s * N_TOK + q);
    const half4v ov = *(const half4_ma*)(Opart + ((size_t)s * DDIM + v) * N_TOK + q);
    num.x += l.x * (float)ov.x; num.y += l.y * (float)ov.y;
    num.z += l.z * (float)ov.z; num.w += l.w * (float)ov.w;
    den.x += l.x; den.y += l.y; den.z += l.z; den.w += l.w;
  }
  *(float4_ma*)(out + o4) =
      make_float4(num.x / den.x, num.y / den.y, num.z / den.z, num.w / den.w);
}

// ---------------- launch ---------------------------------------------------
extern "C" void kernel_launch(void* const* d_in, const int* in_sizes, int n_in,
                              void* d_out, int out_size, void* d_ws, size_t ws_size,
                              hipStream_t stream) {
  const float* x = (const float*)d_in[0];
  float* out = (float*)d_out;
  char* ws = (char*)d_ws;

  // ws: Qf 2MB | Kf 2MB | Vt 2MB | Opart KS*2MB | Lsum KS*32KB
  const size_t need16 = (6u << 20) + 16 * (2u << 20) + (size_t)16 * N_TOK * 4;
  const int KS = (ws_size >= need16) ? 16 : 8;

  _Float16* Qf    = (_Float16*)(ws);
  _Float16* Kf    = (_Float16*)(ws + (2u << 20));
  _Float16* Vt    = (_Float16*)(ws + (4u << 20));
  _Float16* Opart = (_Float16*)(ws + (6u << 20));
  float*    Lsum  = (float*)(ws + (6u << 20) + (size_t)KS * (2u << 20));

  prep_all<<<dim3(3072), dim3(256), 0, stream>>>(x, Qf, Kf, Vt);
  if (KS == 16) {
    flash_attn<16><<<dim3(512), dim3(256), 0, stream>>>(Qf, Kf, Vt, Opart, Lsum);
  } else {
    flash_attn<8><<<dim3(256), dim3(256), 0, stream>>>(Qf, Kf, Vt, Opart, Lsum);
  }
  combine_kernel<<<dim3(1024), dim3(256), 0, stream>>>(Opart, Lsum, out, KS);
}

// Round 16
// 108.237 us; speedup vs baseline: 2.0324x; 1.0769x over previous
//
#include <hip/hip_runtime.h>
#include <hip/hip_bf16.h>
#include <stdint.h>

#define N_TOK 8192
#define DDIM  128

typedef _Float16 half2v __attribute__((ext_vector_type(2)));
typedef _Float16 half4v __attribute__((ext_vector_type(4)));
typedef _Float16 half8v __attribute__((ext_vector_type(8)));
typedef __fp16  fp16x2 __attribute__((ext_vector_type(2)));
typedef float f32x4 __attribute__((ext_vector_type(4)));
typedef half4v half4_ma __attribute__((may_alias));
typedef half8v half8_ma __attribute__((may_alias));
typedef float4 float4_ma __attribute__((may_alias));

#define MFMA32 __builtin_amdgcn_mfma_f32_16x16x32_f16

// 1/sqrt(128) * log2(e): folded into Q so inner loop is a bare v_exp_f32
#define QSCALE (0.08838834764831845f * 1.4426950408889634f)

__device__ __forceinline__ half2v pkrtz(float a, float b) {
  return __builtin_bit_cast(half2v, __builtin_amdgcn_cvt_pkrtz(a, b));
}

#if __has_builtin(__builtin_amdgcn_fdot2)
__device__ __forceinline__ float dot2acc(half2v a, float c) {
  const fp16x2 ones = {(__fp16)1.f, (__fp16)1.f};
  return __builtin_amdgcn_fdot2(__builtin_bit_cast(fp16x2, a), ones, c, false);
}
#else
__device__ __forceinline__ float dot2acc(half2v a, float c) {
  return c + (float)a.x + (float)a.y;
}
#endif

__device__ __forceinline__ void gload_lds16(const _Float16* g, _Float16* l) {
  __builtin_amdgcn_global_load_lds(
      (const __attribute__((address_space(1))) void*)g,
      (__attribute__((address_space(3))) void*)l, 16, 0, 0);
}

// ---------------- fused prep: Q/K transpose + V copy (one launch) ----------
__global__ void prep_all(const float* __restrict__ x,
                         _Float16* __restrict__ Qf, _Float16* __restrict__ Kf,
                         _Float16* __restrict__ Vt) {
  __shared__ float t[32][33];
  const int blk = blockIdx.x, tid = threadIdx.x;
  if (blk < 2048) {
    const int pt = blk & 31, ct = (blk >> 5) & 3, z = blk >> 7;
    const int b = z >> 1, isQ = z & 1;
    const int c0 = (isQ ? 256 : 128) + ct * 32;
    const int p0 = pt * 32;
    const int tx = tid & 31, ty0 = tid >> 5;
    const float* src = x + ((size_t)b * 384 + c0) * 1024 + p0;
#pragma unroll
    for (int i = 0; i < 4; ++i)
      t[ty0 + i * 8][tx] = src[(ty0 + i * 8) * 1024 + tx];
    __syncthreads();
    _Float16* dst = isQ ? Qf : Kf;
    const float sc = isQ ? QSCALE : 1.f;
#pragma unroll
    for (int i = 0; i < 4; ++i) {
      const int ty = ty0 + i * 8;
      dst[((size_t)b * 1024 + p0 + ty) * DDIM + ct * 32 + tx] = (_Float16)(t[tx][ty] * sc);
    }
  } else {
    const int i4 = ((blk - 2048) * 256 + tid) * 4;
    const int v = i4 >> 13, n = i4 & 8191;
    const int b = n >> 10, p = n & 1023;
    const float4 s = *(const float4_ma*)(x + ((size_t)b * 384 + v) * 1024 + p);
    half4v h; h.x = (_Float16)s.x; h.y = (_Float16)s.y; h.z = (_Float16)s.z; h.w = (_Float16)s.w;
    *(half4_ma*)(Vt + (size_t)v * N_TOK + b * 1024 + p) = h;
  }
}

// ---------------- flash attention: QT=4, CK=32, PV at K=32 (sigma trick) ---
// 512 blocks x 256 thr (4 waves x 64 qrows), KS=16 w/ XCD swizzle, 32KB LDS
// dbuf -> 2 blocks/CU. PV contraction index sigma-permuted so S-tile pairs in
// registers ARE the MFMA32 B-operand: sigma(8q+j) = 4q+(j&3)+16*(j>>2).
template<int KS>
__global__ __launch_bounds__(256, 2) void flash_attn(
    const _Float16* __restrict__ Qf, const _Float16* __restrict__ Kf,
    const _Float16* __restrict__ Vt, _Float16* __restrict__ Opart,
    float* __restrict__ Lsum) {
  alignas(16) __shared__ _Float16 lds[16384];  // 2 x (K 8KB + V 8KB) = 32 KB

  const int tid = threadIdx.x;
  const int w = tid >> 6, lane = tid & 63;
  const int quad = lane >> 4, l16 = lane & 15;
  const int blk = blockIdx.x;
  const int ks = (KS == 16) ? (((blk & 7) << 1) | (blk >> 8)) : (blk & 7);
  const int kp = N_TOK / KS;
  const int chunks = kp >> 5;           // CK=32
  const int k0 = ks * kp;
  const int q0 = ((blk >> 3) & 31) * 256;

  // Q fragments resident (B-operand): Q[q=l16][c=quad*8+j], 4 q-tiles
  half8v qf[4][4];
#pragma unroll
  for (int qt = 0; qt < 4; ++qt) {
    const _Float16* qp = Qf + (size_t)(q0 + w * 64 + qt * 16 + l16) * DDIM + quad * 8;
#pragma unroll
    for (int kb = 0; kb < 4; ++kb) qf[qt][kb] = *(const half8_ma*)(qp + kb * 32);
  }

  f32x4 O[4][8];
#pragma unroll
  for (int qt = 0; qt < 4; ++qt)
#pragma unroll
    for (int vb = 0; vb < 8; ++vb) O[qt][vb] = (f32x4){0.f, 0.f, 0.f, 0.f};
  float ls[4] = {0.f, 0.f, 0.f, 0.f};

  // staging: per wave 2 K-instrs + 2 V-instrs per chunk
  const _Float16* srcK[2];
  const _Float16* srcV[2];
  int slotK[2], slotV[2];
#pragma unroll
  for (int j = 0; j < 2; ++j) {
    const int i = w * 2 + j;                    // 0..7
    srcK[j] = Kf + (size_t)(k0 + (lane & 31)) * DDIM + (i * 2 + (lane >> 5)) * 8;
    slotK[j] = i * 512;
    // V: dest v = i*16 + (lane>>2), 16B pair p = lane&3; source pair-swizzled
    const int v = i * 16 + (lane >> 2);
    const int lp = (lane & 3) ^ ((v >> 1) & 3);
    srcV[j] = Vt + (size_t)v * N_TOK + k0 + lp * 8;
    slotV[j] = 4096 + i * 512;
  }

#pragma unroll
  for (int j = 0; j < 2; ++j) {
    gload_lds16(srcK[j], lds + slotK[j]);
    gload_lds16(srcV[j], lds + slotV[j]);
  }

  const int sw = (l16 >> 1) & 3;        // V read un-swizzle key (v>>1)&3
  for (int ch = 0; ch < chunks; ++ch) {
    __syncthreads();
    _Float16* buf = lds + (ch & 1) * 8192;
    if (ch + 1 < chunks) {
      _Float16* nbuf = lds + ((ch + 1) & 1) * 8192;
      const int adv = (ch + 1) * 32;
#pragma unroll
      for (int j = 0; j < 2; ++j) {
        gload_lds16(srcK[j] + (size_t)adv * DDIM, nbuf + slotK[j]);
        gload_lds16(srcV[j] + adv, nbuf + slotV[j]);
      }
    }
    const _Float16* Ksh = buf;
    const _Float16* Vsh = buf + 4096;

    // S^T = K Q^T : C-layout row=key (quad*4+r), col=q (l16); cb = 16-key tile
    f32x4 S[4][2];
#pragma unroll
    for (int qt = 0; qt < 4; ++qt)
#pragma unroll
      for (int cb = 0; cb < 2; ++cb) S[qt][cb] = (f32x4){0.f, 0.f, 0.f, 0.f};
#pragma unroll
    for (int kb = 0; kb < 4; ++kb) {
#pragma unroll
      for (int cb = 0; cb < 2; ++cb) {
        half8v kf = *(const half8_ma*)(Ksh + ((kb * 4 + quad) * 256 + (cb * 16 + l16) * 8));
#pragma unroll
        for (int qt = 0; qt < 4; ++qt)
          S[qt][cb] = MFMA32(kf, qf[qt][kb], S[qt][cb], 0, 0, 0);
      }
    }

    // P = exp2(S); build the full 8-f16 B-operand [cb0 | cb1] directly
    half8v P8[4];
#pragma unroll
    for (int qt = 0; qt < 4; ++qt) {
      const float a0 = __builtin_amdgcn_exp2f(S[qt][0][0]);
      const float a1 = __builtin_amdgcn_exp2f(S[qt][0][1]);
      const float a2 = __builtin_amdgcn_exp2f(S[qt][0][2]);
      const float a3 = __builtin_amdgcn_exp2f(S[qt][0][3]);
      const float b0 = __builtin_amdgcn_exp2f(S[qt][1][0]);
      const float b1 = __builtin_amdgcn_exp2f(S[qt][1][1]);
      const float b2 = __builtin_amdgcn_exp2f(S[qt][1][2]);
      const float b3 = __builtin_amdgcn_exp2f(S[qt][1][3]);
      half2v pa0 = pkrtz(a0, a1), pa1 = pkrtz(a2, a3);
      half2v pb0 = pkrtz(b0, b1), pb1 = pkrtz(b2, b3);
      ls[qt] = dot2acc(pa0, dot2acc(pa1, dot2acc(pb0, dot2acc(pb1, ls[qt]))));
      half4v lo = __builtin_shufflevector(pa0, pa1, 0, 1, 2, 3);
      half4v hi = __builtin_shufflevector(pb0, pb1, 0, 1, 2, 3);
      P8[qt] = __builtin_shufflevector(lo, hi, 0, 1, 2, 3, 4, 5, 6, 7);
    }

    // O^T += V^T P^T via MFMA32 under sigma: lane's A-frag = V keys
    // {4q..4q+3} (half h=quad) and {16+4q..+3} (half h=quad+4), pair-swizzled.
    const int pp1 = (quad >> 1) ^ sw;           // half h=quad   -> 16B pair
    const int pp2 = pp1 ^ 2;                    // half h=quad+4
    const int hh = (quad & 1) * 4;              // 8B half within pair (f16 idx)
#pragma unroll
    for (int vb = 0; vb < 8; ++vb) {
      const int v = vb * 16 + l16;
      half4v lo = *(const half4_ma*)(Vsh + v * 32 + pp1 * 8 + hh);
      half4v hi = *(const half4_ma*)(Vsh + v * 32 + pp2 * 8 + hh);
      half8v vf = __builtin_shufflevector(lo, hi, 0, 1, 2, 3, 4, 5, 6, 7);
#pragma unroll
      for (int qt = 0; qt < 4; ++qt)
        O[qt][vb] = MFMA32(vf, P8[qt], O[qt][vb], 0, 0, 0);
    }
  }

  // epilogue
#pragma unroll
  for (int qt = 0; qt < 4; ++qt) {
    ls[qt] += __shfl_xor(ls[qt], 16, 64);
    ls[qt] += __shfl_xor(ls[qt], 32, 64);
  }
#pragma unroll
  for (int qt = 0; qt < 4; ++qt) {
    const float rl = 1.f / ls[qt];
    const int q = q0 + w * 64 + qt * 16 + l16;
#pragma unroll
    for (int vb = 0; vb < 8; ++vb) {
#pragma unroll
      for (int r = 0; r < 4; ++r) {
        const int v = vb * 16 + quad * 4 + r;
        Opart[((size_t)ks * DDIM + v) * N_TOK + q] = (_Float16)(O[qt][vb][r] * rl);
      }
    }
  }
  if (lane < 16) {
#pragma unroll
    for (int qt = 0; qt < 4; ++qt)
      Lsum[(size_t)ks * N_TOK + q0 + w * 64 + qt * 16 + lane] = ls[qt];
  }
}

// ---------------- combine: float4, l-weighted average ----------------------
__global__ void combine_kernel(const _Float16* __restrict__ Opart,
                               const float* __restrict__ Lsum,
                               float* __restrict__ out, int KS) {
  const int o4 = (blockIdx.x * 256 + threadIdx.x) * 4;
  const int b = o4 >> 17, v = (o4 >> 10) & 127, p = o4 & 1023;
  const int q = (b << 10) | p;
  float4 num = make_float4(0.f, 0.f, 0.f, 0.f);
  float4 den = make_float4(0.f, 0.f, 0.f, 0.f);
  for (int s = 0; s < KS; ++s) {
    const float4 l = *(const float4_ma*)(Lsum + (size_t)s * N_TOK + q);
    const half4v ov = *(const half4_ma*)(Opart + ((size_t)s * DDIM + v) * N_TOK + q);
    num.x += l.x * (float)ov.x; num.y += l.y * (float)ov.y;
    num.z += l.z * (float)ov.z; num.w += l.w * (float)ov.w;
    den.x += l.x; den.y += l.y; den.z += l.z; den.w += l.w;
  }
  *(float4_ma*)(out + o4) =
      make_float4(num.x / den.x, num.y / den.y, num.z / den.z, num.w / den.w);
}

// ---------------- launch ---------------------------------------------------
extern "C" void kernel_launch(void* const* d_in, const int* in_sizes, int n_in,
                              void* d_out, int out_size, void* d_ws, size_t ws_size,
                              hipStream_t stream) {
  const float* x = (const float*)d_in[0];
  float* out = (float*)d_out;
  char* ws = (char*)d_ws;

  // ws: Qf 2MB | Kf 2MB | Vt 2MB | Opart KS*2MB | Lsum KS*32KB
  const size_t need16 = (6u << 20) + 16 * (2u << 20) + (size_t)16 * N_TOK * 4;
  const int KS = (ws_size >= need16) ? 16 : 8;

  _Float16* Qf    = (_Float16*)(ws);
  _Float16* Kf    = (_Float16*)(ws + (2u << 20));
  _Float16* Vt    = (_Float16*)(ws + (4u << 20));
  _Float16* Opart = (_Float16*)(ws + (6u << 20));
  float*    Lsum  = (float*)(ws + (6u << 20) + (size_t)KS * (2u << 20));

  prep_all<<<dim3(3072), dim3(256), 0, stream>>>(x, Qf, Kf, Vt);
  if (KS == 16) {
    flash_attn<16><<<dim3(512), dim3(256), 0, stream>>>(Qf, Kf, Vt, Opart, Lsum);
  } else {
    flash_attn<8><<<dim3(256), dim3(256), 0, stream>>>(Qf, Kf, Vt, Opart, Lsum);
  }
  combine_kernel<<<dim3(1024), dim3(256), 0, stream>>>(Opart, Lsum, out, KS);
}